// Round 3
// baseline (229.344 us; speedup 1.0000x reference)
//
#include <hip/hip_runtime.h>
#include <hip/hip_bf16.h>

typedef __attribute__((ext_vector_type(4))) float floatx4;
typedef __attribute__((ext_vector_type(8))) int   intx8;

#define FP8_MAX_F 448.0f
#define SCALE_EPS 1e-7f

// ---------------- absmax over x: wave shuffle reduce -> LDS -> 1 atomic per block ---------
__global__ void k_absmax(const float* __restrict__ x, unsigned* __restrict__ amax, int n4) {
    __shared__ float wmax[4];
    int tid = blockIdx.x * blockDim.x + threadIdx.x;
    int stride = gridDim.x * blockDim.x;
    const float4* x4 = (const float4*)x;
    float m = 0.f;
    for (int i = tid; i < n4; i += stride) {
        float4 v = x4[i];
        m = fmaxf(fmaxf(fabsf(v.x), fabsf(v.y)),
                  fmaxf(m, fmaxf(fabsf(v.z), fabsf(v.w))));
    }
    #pragma unroll
    for (int off = 32; off > 0; off >>= 1) m = fmaxf(m, __shfl_xor(m, off, 64));
    if ((threadIdx.x & 63) == 0) wmax[threadIdx.x >> 6] = m;
    __syncthreads();
    if (threadIdx.x == 0) {
        float t = fmaxf(fmaxf(wmax[0], wmax[1]), fmaxf(wmax[2], wmax[3]));
        atomicMax(amax, __float_as_uint(t));
    }
}

// ---------------- weight: f32 (e4m3-representable) -> fp8 bytes (exact; ws folded later) --
__global__ void k_quant_w(const float* __restrict__ w, int* __restrict__ wq, int n16) {
    int tid = blockIdx.x * blockDim.x + threadIdx.x;
    int stride = gridDim.x * blockDim.x;
    const float4* x4 = (const float4*)w;
    int4* q4 = (int4*)wq;
    for (int i = tid; i < n16; i += stride) {
        float4 v0 = x4[4*i], v1 = x4[4*i+1], v2 = x4[4*i+2], v3 = x4[4*i+3];
        int4 o;
        o.x = __builtin_amdgcn_cvt_pk_fp8_f32(v0.x, v0.y, 0, false);
        o.x = __builtin_amdgcn_cvt_pk_fp8_f32(v0.z, v0.w, o.x, true);
        o.y = __builtin_amdgcn_cvt_pk_fp8_f32(v1.x, v1.y, 0, false);
        o.y = __builtin_amdgcn_cvt_pk_fp8_f32(v1.z, v1.w, o.y, true);
        o.z = __builtin_amdgcn_cvt_pk_fp8_f32(v2.x, v2.y, 0, false);
        o.z = __builtin_amdgcn_cvt_pk_fp8_f32(v2.z, v2.w, o.z, true);
        o.w = __builtin_amdgcn_cvt_pk_fp8_f32(v3.x, v3.y, 0, false);
        o.w = __builtin_amdgcn_cvt_pk_fp8_f32(v3.z, v3.w, o.w, true);
        q4[i] = o;
    }
}

// ---------------- x: f32 -> e4m3 bytes (HW RNE), scale = max(absmax/448, eps) -------------
__global__ void k_quant_x(const float* __restrict__ x, int* __restrict__ xq,
                          const unsigned* __restrict__ amax, int n16) {
    float scale = fmaxf(__uint_as_float(*amax) / FP8_MAX_F, SCALE_EPS);
    int tid = blockIdx.x * blockDim.x + threadIdx.x;
    int stride = gridDim.x * blockDim.x;
    const float4* x4 = (const float4*)x;
    int4* q4 = (int4*)xq;
    for (int i = tid; i < n16; i += stride) {
        float4 v0 = x4[4*i], v1 = x4[4*i+1], v2 = x4[4*i+2], v3 = x4[4*i+3];
        int4 o;
        o.x = __builtin_amdgcn_cvt_pk_fp8_f32(v0.x / scale, v0.y / scale, 0, false);
        o.x = __builtin_amdgcn_cvt_pk_fp8_f32(v0.z / scale, v0.w / scale, o.x, true);
        o.y = __builtin_amdgcn_cvt_pk_fp8_f32(v1.x / scale, v1.y / scale, 0, false);
        o.y = __builtin_amdgcn_cvt_pk_fp8_f32(v1.z / scale, v1.w / scale, o.y, true);
        o.z = __builtin_amdgcn_cvt_pk_fp8_f32(v2.x / scale, v2.y / scale, 0, false);
        o.z = __builtin_amdgcn_cvt_pk_fp8_f32(v2.z / scale, v2.w / scale, o.z, true);
        o.w = __builtin_amdgcn_cvt_pk_fp8_f32(v3.x / scale, v3.y / scale, 0, false);
        o.w = __builtin_amdgcn_cvt_pk_fp8_f32(v3.z / scale, v3.w / scale, o.w, true);
        q4[i] = o;
    }
}

// ================= 256x256 8-wave phase-split MX-fp8 GEMM ================================
// C[M,N] = ws * (A[M,K]fp8 . B[N,K]fp8^T) + bias.  Slab = 128 fp8-K (one 16x16x128 step).
// 2-deep LDS double buffer (128 KiB), 4 phases/slab, counted vmcnt(4) at phase 0 only,
// raw s_barrier (+"memory"), setprio around MFMA clusters, c^(r&7) chunk swizzle (T2).
#define BM 256
#define BN 256
#define BKQ 128
#define NT 16   // K / BKQ, K = 2048 fixed

#define GLOAD(src, dst) \
    __builtin_amdgcn_global_load_lds((const __attribute__((address_space(1))) void*)(src), \
                                     (__attribute__((address_space(3))) void*)(dst), 16, 0, 0)
#define BARRIER()  asm volatile("s_barrier" ::: "memory")
#define WAIT_VM(n) asm volatile("s_waitcnt vmcnt(" #n ")" ::: "memory")
#define WAIT_LGKM() asm volatile("s_waitcnt lgkmcnt(0)" ::: "memory")

__device__ __forceinline__ intx8 ldfrag(const unsigned char* base, int r, int g) {
    int c0 = (2 * g) ^ (r & 7);
    const int4 lo = *(const int4*)(base + r * 128 + c0 * 16);
    const int4 hi = *(const int4*)(base + r * 128 + (c0 ^ 1) * 16);
    return (intx8){lo.x, lo.y, lo.z, lo.w, hi.x, hi.y, hi.z, hi.w};
}

#define MFMA_ROW(m, af)                                                            \
    acc[m][0] = __builtin_amdgcn_mfma_scale_f32_16x16x128_f8f6f4(                  \
        af, b[0], acc[m][0], 0, 0, 0, 0x7F7F7F7F, 0, 0x7F7F7F7F);                  \
    acc[m][1] = __builtin_amdgcn_mfma_scale_f32_16x16x128_f8f6f4(                  \
        af, b[1], acc[m][1], 0, 0, 0, 0x7F7F7F7F, 0, 0x7F7F7F7F);                  \
    acc[m][2] = __builtin_amdgcn_mfma_scale_f32_16x16x128_f8f6f4(                  \
        af, b[2], acc[m][2], 0, 0, 0, 0x7F7F7F7F, 0, 0x7F7F7F7F);                  \
    acc[m][3] = __builtin_amdgcn_mfma_scale_f32_16x16x128_f8f6f4(                  \
        af, b[3], acc[m][3], 0, 0, 0, 0x7F7F7F7F, 0, 0x7F7F7F7F);

__global__ __launch_bounds__(512, 2) void k_gemm_mx(
    const unsigned char* __restrict__ A, const unsigned char* __restrict__ B,
    const float* __restrict__ bias, const float* __restrict__ wscale,
    float* __restrict__ C, int M, int N, int K) {
    __shared__ __align__(16) unsigned char lds[131072];   // [buf:2][A 32K | B 32K]

    int nwg = gridDim.x;
    int bid = blockIdx.x;
    bid = (bid & 7) * (nwg >> 3) + (bid >> 3);   // XCD swizzle (nwg % 8 == 0)
    int ntn = N / BN;
    int tm = bid / ntn, tn = bid % ntn;
    int row0 = tm * BM, col0 = tn * BN;

    int tid = (int)threadIdx.x;
    int lane = tid & 63, wid = tid >> 6;
    int wr = wid >> 2, wc = wid & 3;             // 2M x 4N waves; per-wave 128x64
    int fr = lane & 15, g = lane >> 4;

    // staging geometry: instr i (0..3) per operand; chunk p = i*512 + tid (16 B each);
    // physical LDS linear (dest = p*16); logical source chunk col = (p&7) ^ (row&7).
    int offA[4], offB[4], ldso[4];
    #pragma unroll
    for (int i = 0; i < 4; ++i) {
        int p = i * 512 + tid;
        int r = p >> 3;
        int c = (p & 7) ^ (r & 7);
        offA[i] = (row0 + r) * K + c * 16;
        offB[i] = (col0 + r) * K + c * 16;
        ldso[i] = p * 16;
    }

    floatx4 acc[8][4];
    #pragma unroll
    for (int m = 0; m < 8; ++m)
        #pragma unroll
        for (int n = 0; n < 4; ++n) acc[m][n] = (floatx4)(0.f);

    // prologue: stage slab 0 into buf0 (8 loads); waited by loop's first vmcnt(4)+barrier
    {
        unsigned char* An = lds;
        unsigned char* Bn = lds + 32768;
        #pragma unroll
        for (int i = 0; i < 4; ++i) GLOAD(A + offA[i], An + ldso[i]);
        #pragma unroll
        for (int i = 0; i < 4; ++i) GLOAD(B + offB[i], Bn + ldso[i]);
    }

    #pragma unroll 2
    for (int t = 0; t < NT; ++t) {
        const int buf = t & 1;
        const unsigned char* Ab = lds + buf * 65536;
        const unsigned char* Bb = Ab + 32768;
        unsigned char* An = lds + (buf ^ 1) * 65536;
        unsigned char* Bn = An + 32768;
        const int ktn = ((t + 1) & (NT - 1)) * BKQ;   // wrap keeps schedule uniform

        // ---- phase 0: stage 4 of next slab; counted wait for THIS slab; B0-3 + A0-1
        GLOAD(A + ktn + offA[0], An + ldso[0]);
        GLOAD(A + ktn + offA[1], An + ldso[1]);
        GLOAD(B + ktn + offB[0], Bn + ldso[0]);
        GLOAD(B + ktn + offB[1], Bn + ldso[1]);
        WAIT_VM(4);          // all but the 4 just-issued retired -> this slab's LDS valid
        BARRIER();
        intx8 b[4];
        #pragma unroll
        for (int n = 0; n < 4; ++n) b[n] = ldfrag(Bb, wc * 64 + n * 16 + fr, g);
        intx8 a0 = ldfrag(Ab, wr * 128 + 0 * 16 + fr, g);
        intx8 a1 = ldfrag(Ab, wr * 128 + 1 * 16 + fr, g);
        WAIT_LGKM();
        __builtin_amdgcn_sched_barrier(0);
        __builtin_amdgcn_s_setprio(1);
        MFMA_ROW(0, a0)
        MFMA_ROW(1, a1)
        __builtin_amdgcn_s_setprio(0);
        BARRIER();

        // ---- phase 1: stage remaining 4; A2-3
        GLOAD(A + ktn + offA[2], An + ldso[2]);
        GLOAD(A + ktn + offA[3], An + ldso[3]);
        GLOAD(B + ktn + offB[2], Bn + ldso[2]);
        GLOAD(B + ktn + offB[3], Bn + ldso[3]);
        a0 = ldfrag(Ab, wr * 128 + 2 * 16 + fr, g);
        a1 = ldfrag(Ab, wr * 128 + 3 * 16 + fr, g);
        BARRIER();
        WAIT_LGKM();
        __builtin_amdgcn_sched_barrier(0);
        __builtin_amdgcn_s_setprio(1);
        MFMA_ROW(2, a0)
        MFMA_ROW(3, a1)
        __builtin_amdgcn_s_setprio(0);
        BARRIER();

        // ---- phase 2: A4-5
        a0 = ldfrag(Ab, wr * 128 + 4 * 16 + fr, g);
        a1 = ldfrag(Ab, wr * 128 + 5 * 16 + fr, g);
        BARRIER();
        WAIT_LGKM();
        __builtin_amdgcn_sched_barrier(0);
        __builtin_amdgcn_s_setprio(1);
        MFMA_ROW(4, a0)
        MFMA_ROW(5, a1)
        __builtin_amdgcn_s_setprio(0);
        BARRIER();

        // ---- phase 3: A6-7
        a0 = ldfrag(Ab, wr * 128 + 6 * 16 + fr, g);
        a1 = ldfrag(Ab, wr * 128 + 7 * 16 + fr, g);
        BARRIER();
        WAIT_LGKM();
        __builtin_amdgcn_sched_barrier(0);
        __builtin_amdgcn_s_setprio(1);
        MFMA_ROW(6, a0)
        MFMA_ROW(7, a1)
        __builtin_amdgcn_s_setprio(0);
        BARRIER();
    }

    WAIT_VM(0);   // drain wrap-around staging before exit path

    // epilogue: C/D layout (shape-determined): col=lane&15, row=(lane>>4)*4+j
    float wsv = *wscale;
    int crow = (lane >> 4) * 4;
    int ccol = lane & 15;
    float bv[4];
    #pragma unroll
    for (int n = 0; n < 4; ++n) bv[n] = bias[col0 + wc * 64 + n * 16 + ccol];
    #pragma unroll
    for (int m = 0; m < 8; ++m) {
        int r = row0 + wr * 128 + m * 16 + crow;
        #pragma unroll
        for (int n = 0; n < 4; ++n) {
            int c = col0 + wc * 64 + n * 16 + ccol;
            #pragma unroll
            for (int j = 0; j < 4; ++j)
                C[(long)(r + j) * N + c] = acc[m][n][j] * wsv + bv[n];
        }
    }
}

extern "C" void kernel_launch(void* const* d_in, const int* in_sizes, int n_in,
                              void* d_out, int out_size, void* d_ws, size_t ws_size,
                              hipStream_t stream) {
    const float* x      = (const float*)d_in[0];
    const float* w      = (const float*)d_in[1];
    const float* wscale = (const float*)d_in[2];
    const float* bias   = (const float*)d_in[3];
    float* out = (float*)d_out;

    const int K = 2048, N = 2048;
    const int M = in_sizes[0] / K;     // 16384

    unsigned char* ws = (unsigned char*)d_ws;
    unsigned* amax = (unsigned*)ws;                          // 4 B
    int* wq = (int*)(ws + 1024);                             // N*K   = 4.2 MB fp8
    int* xq = (int*)(ws + 1024 + (size_t)N * K);             // M*K   = 33.5 MB fp8

    hipMemsetAsync(amax, 0, 4, stream);
    k_absmax<<<2048, 256, 0, stream>>>(x, amax, (M * K) / 4);
    k_quant_w<<<1024, 256, 0, stream>>>(w, wq, (N * K) / 16);
    k_quant_x<<<2048, 256, 0, stream>>>(x, xq, amax, (M * K) / 16);

    int grid = (M / BM) * (N / BN);    // 64 * 8 = 512
    k_gemm_mx<<<grid, 512, 0, stream>>>((const unsigned char*)xq, (const unsigned char*)wq,
                                        bias, wscale, out, M, N, K);
}

// Round 4
// 177.920 us; speedup vs baseline: 1.2890x; 1.2890x over previous
//
#include <hip/hip_runtime.h>
#include <hip/hip_bf16.h>

typedef __attribute__((ext_vector_type(4))) float floatx4;
typedef __attribute__((ext_vector_type(8))) int   intx8;

#define FP8_MAX_F 448.0f
#define SCALE_EPS 1e-7f

// ---------------- absmax over x: wave shuffle reduce -> LDS -> 1 atomic per block ---------
__global__ void k_absmax(const float* __restrict__ x, unsigned* __restrict__ amax, int n4) {
    __shared__ float wmax[4];
    int tid = blockIdx.x * blockDim.x + threadIdx.x;
    int stride = gridDim.x * blockDim.x;
    const float4* x4 = (const float4*)x;
    float m = 0.f;
    for (int i = tid; i < n4; i += stride) {
        float4 v = x4[i];
        m = fmaxf(fmaxf(fabsf(v.x), fabsf(v.y)),
                  fmaxf(m, fmaxf(fabsf(v.z), fabsf(v.w))));
    }
    #pragma unroll
    for (int off = 32; off > 0; off >>= 1) m = fmaxf(m, __shfl_xor(m, off, 64));
    if ((threadIdx.x & 63) == 0) wmax[threadIdx.x >> 6] = m;
    __syncthreads();
    if (threadIdx.x == 0) {
        float t = fmaxf(fmaxf(wmax[0], wmax[1]), fmaxf(wmax[2], wmax[3]));
        atomicMax(amax, __float_as_uint(t));
    }
}

// ---------------- weight: f32 (e4m3-representable) -> fp8 bytes (exact; ws folded later) --
__global__ void k_quant_w(const float* __restrict__ w, int* __restrict__ wq, int n16) {
    int tid = blockIdx.x * blockDim.x + threadIdx.x;
    int stride = gridDim.x * blockDim.x;
    const float4* x4 = (const float4*)w;
    int4* q4 = (int4*)wq;
    for (int i = tid; i < n16; i += stride) {
        float4 v0 = x4[4*i], v1 = x4[4*i+1], v2 = x4[4*i+2], v3 = x4[4*i+3];
        int4 o;
        o.x = __builtin_amdgcn_cvt_pk_fp8_f32(v0.x, v0.y, 0, false);
        o.x = __builtin_amdgcn_cvt_pk_fp8_f32(v0.z, v0.w, o.x, true);
        o.y = __builtin_amdgcn_cvt_pk_fp8_f32(v1.x, v1.y, 0, false);
        o.y = __builtin_amdgcn_cvt_pk_fp8_f32(v1.z, v1.w, o.y, true);
        o.z = __builtin_amdgcn_cvt_pk_fp8_f32(v2.x, v2.y, 0, false);
        o.z = __builtin_amdgcn_cvt_pk_fp8_f32(v2.z, v2.w, o.z, true);
        o.w = __builtin_amdgcn_cvt_pk_fp8_f32(v3.x, v3.y, 0, false);
        o.w = __builtin_amdgcn_cvt_pk_fp8_f32(v3.z, v3.w, o.w, true);
        q4[i] = o;
    }
}

// ---------------- x: f32 -> e4m3 bytes (HW RNE), scale = max(absmax/448, eps) -------------
__global__ void k_quant_x(const float* __restrict__ x, int* __restrict__ xq,
                          const unsigned* __restrict__ amax, int n16) {
    float scale = fmaxf(__uint_as_float(*amax) / FP8_MAX_F, SCALE_EPS);
    int tid = blockIdx.x * blockDim.x + threadIdx.x;
    int stride = gridDim.x * blockDim.x;
    const float4* x4 = (const float4*)x;
    int4* q4 = (int4*)xq;
    for (int i = tid; i < n16; i += stride) {
        float4 v0 = x4[4*i], v1 = x4[4*i+1], v2 = x4[4*i+2], v3 = x4[4*i+3];
        int4 o;
        o.x = __builtin_amdgcn_cvt_pk_fp8_f32(v0.x / scale, v0.y / scale, 0, false);
        o.x = __builtin_amdgcn_cvt_pk_fp8_f32(v0.z / scale, v0.w / scale, o.x, true);
        o.y = __builtin_amdgcn_cvt_pk_fp8_f32(v1.x / scale, v1.y / scale, 0, false);
        o.y = __builtin_amdgcn_cvt_pk_fp8_f32(v1.z / scale, v1.w / scale, o.y, true);
        o.z = __builtin_amdgcn_cvt_pk_fp8_f32(v2.x / scale, v2.y / scale, 0, false);
        o.z = __builtin_amdgcn_cvt_pk_fp8_f32(v2.z / scale, v2.w / scale, o.z, true);
        o.w = __builtin_amdgcn_cvt_pk_fp8_f32(v3.x / scale, v3.y / scale, 0, false);
        o.w = __builtin_amdgcn_cvt_pk_fp8_f32(v3.z / scale, v3.w / scale, o.w, true);
        q4[i] = o;
    }
}

// ================= 256x256 8-wave phase-split MX-fp8 GEMM (spill-free addressing) =========
// C[M,N] = ws * (A[M,K]fp8 . B[N,K]fp8^T) + bias.  Slab = 128 fp8-K (one 16x16x128 step).
// 2-deep LDS dbuf (128 KiB), 4 phases/slab, counted vmcnt(4) once/slab, raw s_barrier,
// setprio around MFMA, c^(r&7) chunk swizzle (both sides). All frag ds_reads use 4 lane
// base pointers + compile-time offsets (r&7 == fr&7 for every fragment row).
#define BM 256
#define BN 256
#define BKQ 128
#define NT 16   // K / BKQ, K = 2048 fixed

#define GLOAD(src, dst) \
    __builtin_amdgcn_global_load_lds((const __attribute__((address_space(1))) void*)(src), \
                                     (__attribute__((address_space(3))) void*)(dst), 16, 0, 0)
#define BARRIER()  asm volatile("s_barrier" ::: "memory")
#define WAIT_VM(n) asm volatile("s_waitcnt vmcnt(" #n ")" ::: "memory")
#define WAIT_LGKM() asm volatile("s_waitcnt lgkmcnt(0)" ::: "memory")

#define LDFRAG(dstv, pL, pH, IMM) {                      \
    int4 lo_ = *(const int4*)((pL) + (IMM));             \
    int4 hi_ = *(const int4*)((pH) + (IMM));             \
    dstv = (intx8){lo_.x, lo_.y, lo_.z, lo_.w, hi_.x, hi_.y, hi_.z, hi_.w}; }

#define MFMA_ROW(m, af)                                                            \
    acc[m][0] = __builtin_amdgcn_mfma_scale_f32_16x16x128_f8f6f4(                  \
        af, b[0], acc[m][0], 0, 0, 0, 0x7F7F7F7F, 0, 0x7F7F7F7F);                  \
    acc[m][1] = __builtin_amdgcn_mfma_scale_f32_16x16x128_f8f6f4(                  \
        af, b[1], acc[m][1], 0, 0, 0, 0x7F7F7F7F, 0, 0x7F7F7F7F);                  \
    acc[m][2] = __builtin_amdgcn_mfma_scale_f32_16x16x128_f8f6f4(                  \
        af, b[2], acc[m][2], 0, 0, 0, 0x7F7F7F7F, 0, 0x7F7F7F7F);                  \
    acc[m][3] = __builtin_amdgcn_mfma_scale_f32_16x16x128_f8f6f4(                  \
        af, b[3], acc[m][3], 0, 0, 0, 0x7F7F7F7F, 0, 0x7F7F7F7F);

__global__ __launch_bounds__(512, 2) void k_gemm_mx(
    const unsigned char* __restrict__ A, const unsigned char* __restrict__ B,
    const float* __restrict__ bias, const float* __restrict__ wscale,
    float* __restrict__ C, int M, int N, int K) {
    __shared__ __align__(16) unsigned char lds[131072];   // [buf:2][A 32K | B 32K]

    int nwg = gridDim.x;
    int bid = blockIdx.x;
    bid = (bid & 7) * (nwg >> 3) + (bid >> 3);   // XCD swizzle (nwg % 8 == 0)
    int ntn = N / BN;
    int tm = bid / ntn, tn = bid % ntn;
    int row0 = tm * BM, col0 = tn * BN;

    int tid = (int)threadIdx.x;
    int lane = tid & 63, wid = tid >> 6;
    int wr = wid >> 2, wc = wid & 3;             // 2M x 4N waves; per-wave 128x64
    int fr = lane & 15, g = lane >> 4;

    // ---- staging: lane's global byte offset (i-invariant swizzle) + linear LDS dest
    int srow = tid >> 3;                          // 0..63
    int sc   = (tid & 7) ^ (srow & 7);            // logical chunk col (i*64 == 0 mod 8)
    const int offA0 = (row0 + srow) * K + sc * 16;    // + i*131072 + kt
    const int offB0 = (col0 + srow) * K + sc * 16;
    unsigned char* dstA = lds + tid * 16;             // + i*8192 + buf*65536
    unsigned char* dstB = dstA + 32768;

    // ---- fragment bases: r&7 == fr&7 for all fragment rows -> one swizzle per lane
    int c0 = (2 * g) ^ (fr & 7);
    const int aL = wr * 16384 + fr * 128 + c0 * 16;        // + m*2048
    const int aH = wr * 16384 + fr * 128 + (c0 ^ 1) * 16;
    const int bL = 32768 + wc * 8192 + fr * 128 + c0 * 16; // + n*2048
    const int bH = 32768 + wc * 8192 + fr * 128 + (c0 ^ 1) * 16;

    floatx4 acc[8][4];
    #pragma unroll
    for (int m = 0; m < 8; ++m)
        #pragma unroll
        for (int n = 0; n < 4; ++n) acc[m][n] = (floatx4)(0.f);

    // prologue: stage slab 0 into buf0 (8 loads)
    GLOAD(A + offA0,          dstA);
    GLOAD(A + offA0 + 131072, dstA + 8192);
    GLOAD(A + offA0 + 262144, dstA + 16384);
    GLOAD(A + offA0 + 393216, dstA + 24576);
    GLOAD(B + offB0,          dstB);
    GLOAD(B + offB0 + 131072, dstB + 8192);
    GLOAD(B + offB0 + 262144, dstB + 16384);
    GLOAD(B + offB0 + 393216, dstB + 24576);

    for (int t = 0; t < NT; ++t) {
        const int bufo = (t & 1) << 16;
        const int nbufo = bufo ^ 65536;
        const unsigned char* AbL = lds + bufo + aL;
        const unsigned char* AbH = lds + bufo + aH;
        const unsigned char* BbL = lds + bufo + bL;
        const unsigned char* BbH = lds + bufo + bH;
        unsigned char* dA = dstA + nbufo;
        unsigned char* dB = dstB + nbufo;
        const int kn = ((t + 1) & (NT - 1)) * BKQ;   // wrap keeps schedule uniform

        intx8 b[4], a0, a1;

        // ---- phase 0: stage 4 of slab t+1; counted wait for slab t; MFMA rows 0-1
        GLOAD(A + kn + offA0,          dA);
        GLOAD(A + kn + offA0 + 131072, dA + 8192);
        GLOAD(B + kn + offB0,          dB);
        GLOAD(B + kn + offB0 + 131072, dB + 8192);
        WAIT_VM(4);          // slab t's 8 loads retired; the 4 just-issued remain
        BARRIER();
        LDFRAG(b[0], BbL, BbH, 0)
        LDFRAG(b[1], BbL, BbH, 2048)
        LDFRAG(b[2], BbL, BbH, 4096)
        LDFRAG(b[3], BbL, BbH, 6144)
        LDFRAG(a0, AbL, AbH, 0)
        LDFRAG(a1, AbL, AbH, 2048)
        WAIT_LGKM();
        __builtin_amdgcn_sched_barrier(0);
        __builtin_amdgcn_s_setprio(1);
        MFMA_ROW(0, a0)
        MFMA_ROW(1, a1)
        __builtin_amdgcn_s_setprio(0);
        BARRIER();

        // ---- phase 1: stage remaining 4 of slab t+1; MFMA rows 2-3
        GLOAD(A + kn + offA0 + 262144, dA + 16384);
        GLOAD(A + kn + offA0 + 393216, dA + 24576);
        GLOAD(B + kn + offB0 + 262144, dB + 16384);
        GLOAD(B + kn + offB0 + 393216, dB + 24576);
        LDFRAG(a0, AbL, AbH, 4096)
        LDFRAG(a1, AbL, AbH, 6144)
        BARRIER();
        WAIT_LGKM();
        __builtin_amdgcn_sched_barrier(0);
        __builtin_amdgcn_s_setprio(1);
        MFMA_ROW(2, a0)
        MFMA_ROW(3, a1)
        __builtin_amdgcn_s_setprio(0);
        BARRIER();

        // ---- phase 2: MFMA rows 4-5
        LDFRAG(a0, AbL, AbH, 8192)
        LDFRAG(a1, AbL, AbH, 10240)
        BARRIER();
        WAIT_LGKM();
        __builtin_amdgcn_sched_barrier(0);
        __builtin_amdgcn_s_setprio(1);
        MFMA_ROW(4, a0)
        MFMA_ROW(5, a1)
        __builtin_amdgcn_s_setprio(0);
        BARRIER();

        // ---- phase 3: MFMA rows 6-7
        LDFRAG(a0, AbL, AbH, 12288)
        LDFRAG(a1, AbL, AbH, 14336)
        BARRIER();
        WAIT_LGKM();
        __builtin_amdgcn_sched_barrier(0);
        __builtin_amdgcn_s_setprio(1);
        MFMA_ROW(6, a0)
        MFMA_ROW(7, a1)
        __builtin_amdgcn_s_setprio(0);
        BARRIER();
    }

    WAIT_VM(0);   // drain wrap-around staging before exit

    // epilogue: C/D layout (shape-determined): col=lane&15, row=(lane>>4)*4+j
    float wsv = *wscale;
    int crow = (lane >> 4) * 4;
    int ccol = lane & 15;
    float bv[4];
    #pragma unroll
    for (int n = 0; n < 4; ++n) bv[n] = bias[col0 + wc * 64 + n * 16 + ccol];
    #pragma unroll
    for (int m = 0; m < 8; ++m) {
        int r = row0 + wr * 128 + m * 16 + crow;
        #pragma unroll
        for (int n = 0; n < 4; ++n) {
            int c = col0 + wc * 64 + n * 16 + ccol;
            #pragma unroll
            for (int j = 0; j < 4; ++j)
                C[(long)(r + j) * N + c] = acc[m][n][j] * wsv + bv[n];
        }
    }
}

extern "C" void kernel_launch(void* const* d_in, const int* in_sizes, int n_in,
                              void* d_out, int out_size, void* d_ws, size_t ws_size,
                              hipStream_t stream) {
    const float* x      = (const float*)d_in[0];
    const float* w      = (const float*)d_in[1];
    const float* wscale = (const float*)d_in[2];
    const float* bias   = (const float*)d_in[3];
    float* out = (float*)d_out;

    const int K = 2048, N = 2048;
    const int M = in_sizes[0] / K;     // 16384

    unsigned char* ws = (unsigned char*)d_ws;
    unsigned* amax = (unsigned*)ws;                          // 4 B
    int* wq = (int*)(ws + 1024);                             // N*K   = 4.2 MB fp8
    int* xq = (int*)(ws + 1024 + (size_t)N * K);             // M*K   = 33.5 MB fp8

    hipMemsetAsync(amax, 0, 4, stream);
    k_absmax<<<2048, 256, 0, stream>>>(x, amax, (M * K) / 4);
    k_quant_w<<<1024, 256, 0, stream>>>(w, wq, (N * K) / 16);
    k_quant_x<<<2048, 256, 0, stream>>>(x, xq, amax, (M * K) / 16);

    int grid = (M / BM) * (N / BN);    // 64 * 8 = 512
    k_gemm_mx<<<grid, 512, 0, stream>>>((const unsigned char*)xq, (const unsigned char*)wq,
                                        bias, wscale, out, M, N, K);
}

// Round 5
// 164.028 us; speedup vs baseline: 1.3982x; 1.0847x over previous
//
#include <hip/hip_runtime.h>
#include <hip/hip_bf16.h>

typedef __attribute__((ext_vector_type(4))) float floatx4;
typedef __attribute__((ext_vector_type(8))) int   intx8;

#define FP8_MAX_F 448.0f
#define SCALE_EPS 1e-7f

// ---------------- absmax over x: wave shuffle reduce -> LDS -> 1 atomic per block ---------
__global__ void k_absmax(const float* __restrict__ x, unsigned* __restrict__ amax, int n4) {
    __shared__ float wmax[4];
    int tid = blockIdx.x * blockDim.x + threadIdx.x;
    int stride = gridDim.x * blockDim.x;
    const float4* x4 = (const float4*)x;
    float m = 0.f;
    for (int i = tid; i < n4; i += stride) {
        float4 v = x4[i];
        m = fmaxf(fmaxf(fabsf(v.x), fabsf(v.y)),
                  fmaxf(m, fmaxf(fabsf(v.z), fabsf(v.w))));
    }
    #pragma unroll
    for (int off = 32; off > 0; off >>= 1) m = fmaxf(m, __shfl_xor(m, off, 64));
    if ((threadIdx.x & 63) == 0) wmax[threadIdx.x >> 6] = m;
    __syncthreads();
    if (threadIdx.x == 0) {
        float t = fmaxf(fmaxf(wmax[0], wmax[1]), fmaxf(wmax[2], wmax[3]));
        atomicMax(amax, __float_as_uint(t));
    }
}

// ---------------- weight: f32 (e4m3-representable) -> fp8 bytes (exact; ws folded later) --
__global__ void k_quant_w(const float* __restrict__ w, int* __restrict__ wq, int n16) {
    int tid = blockIdx.x * blockDim.x + threadIdx.x;
    int stride = gridDim.x * blockDim.x;
    const float4* x4 = (const float4*)w;
    int4* q4 = (int4*)wq;
    for (int i = tid; i < n16; i += stride) {
        float4 v0 = x4[4*i], v1 = x4[4*i+1], v2 = x4[4*i+2], v3 = x4[4*i+3];
        int4 o;
        o.x = __builtin_amdgcn_cvt_pk_fp8_f32(v0.x, v0.y, 0, false);
        o.x = __builtin_amdgcn_cvt_pk_fp8_f32(v0.z, v0.w, o.x, true);
        o.y = __builtin_amdgcn_cvt_pk_fp8_f32(v1.x, v1.y, 0, false);
        o.y = __builtin_amdgcn_cvt_pk_fp8_f32(v1.z, v1.w, o.y, true);
        o.z = __builtin_amdgcn_cvt_pk_fp8_f32(v2.x, v2.y, 0, false);
        o.z = __builtin_amdgcn_cvt_pk_fp8_f32(v2.z, v2.w, o.z, true);
        o.w = __builtin_amdgcn_cvt_pk_fp8_f32(v3.x, v3.y, 0, false);
        o.w = __builtin_amdgcn_cvt_pk_fp8_f32(v3.z, v3.w, o.w, true);
        q4[i] = o;
    }
}

// ---------------- x: f32 -> e4m3 bytes (HW RNE), scale = max(absmax/448, eps) -------------
__global__ void k_quant_x(const float* __restrict__ x, int* __restrict__ xq,
                          const unsigned* __restrict__ amax, int n16) {
    float scale = fmaxf(__uint_as_float(*amax) / FP8_MAX_F, SCALE_EPS);
    int tid = blockIdx.x * blockDim.x + threadIdx.x;
    int stride = gridDim.x * blockDim.x;
    const float4* x4 = (const float4*)x;
    int4* q4 = (int4*)xq;
    for (int i = tid; i < n16; i += stride) {
        float4 v0 = x4[4*i], v1 = x4[4*i+1], v2 = x4[4*i+2], v3 = x4[4*i+3];
        int4 o;
        o.x = __builtin_amdgcn_cvt_pk_fp8_f32(v0.x / scale, v0.y / scale, 0, false);
        o.x = __builtin_amdgcn_cvt_pk_fp8_f32(v0.z / scale, v0.w / scale, o.x, true);
        o.y = __builtin_amdgcn_cvt_pk_fp8_f32(v1.x / scale, v1.y / scale, 0, false);
        o.y = __builtin_amdgcn_cvt_pk_fp8_f32(v1.z / scale, v1.w / scale, o.y, true);
        o.z = __builtin_amdgcn_cvt_pk_fp8_f32(v2.x / scale, v2.y / scale, 0, false);
        o.z = __builtin_amdgcn_cvt_pk_fp8_f32(v2.z / scale, v2.w / scale, o.z, true);
        o.w = __builtin_amdgcn_cvt_pk_fp8_f32(v3.x / scale, v3.y / scale, 0, false);
        o.w = __builtin_amdgcn_cvt_pk_fp8_f32(v3.z / scale, v3.w / scale, o.w, true);
        q4[i] = o;
    }
}

// ================= 256x256 8-wave MX-fp8 GEMM: 2-barrier/slab, counted vmcnt+lgkmcnt ======
// C[M,N] = ws * (A[M,K]fp8 . B[N,K]fp8^T) + bias.  Slab = 128 fp8-K (one 16x16x128 step).
// Per slab: issue 8 gloads(t+1) -> vmcnt(8) -> barrier -> ds_read stream in 4 groups,
// one group ahead, counted lgkmcnt(4) (DS returns in-order) -> end barrier. No full drains.
#define BM 256
#define BN 256
#define BKQ 128
#define NT 16   // K / BKQ, K = 2048 fixed

#define GLOAD(src, dst) \
    __builtin_amdgcn_global_load_lds((const __attribute__((address_space(1))) void*)(src), \
                                     (__attribute__((address_space(3))) void*)(dst), 16, 0, 0)
#define BARRIER()   asm volatile("s_barrier" ::: "memory")
#define WAIT_VM(n)  asm volatile("s_waitcnt vmcnt(" #n ")" ::: "memory")
#define WAIT_LGKM(n) asm volatile("s_waitcnt lgkmcnt(" #n ")" ::: "memory")
#define SB0()       __builtin_amdgcn_sched_barrier(0)

#define LDFRAG(dstv, pL, pH, IMM) {                      \
    int4 lo_ = *(const int4*)((pL) + (IMM));             \
    int4 hi_ = *(const int4*)((pH) + (IMM));             \
    dstv = (intx8){lo_.x, lo_.y, lo_.z, lo_.w, hi_.x, hi_.y, hi_.z, hi_.w}; }

#define MFMA_ROW(m, af)                                                            \
    acc[m][0] = __builtin_amdgcn_mfma_scale_f32_16x16x128_f8f6f4(                  \
        af, b0, acc[m][0], 0, 0, 0, 0x7F7F7F7F, 0, 0x7F7F7F7F);                    \
    acc[m][1] = __builtin_amdgcn_mfma_scale_f32_16x16x128_f8f6f4(                  \
        af, b1, acc[m][1], 0, 0, 0, 0x7F7F7F7F, 0, 0x7F7F7F7F);                    \
    acc[m][2] = __builtin_amdgcn_mfma_scale_f32_16x16x128_f8f6f4(                  \
        af, b2, acc[m][2], 0, 0, 0, 0x7F7F7F7F, 0, 0x7F7F7F7F);                    \
    acc[m][3] = __builtin_amdgcn_mfma_scale_f32_16x16x128_f8f6f4(                  \
        af, b3, acc[m][3], 0, 0, 0, 0x7F7F7F7F, 0, 0x7F7F7F7F);

__global__ __launch_bounds__(512, 2) void k_gemm_mx(
    const unsigned char* __restrict__ A, const unsigned char* __restrict__ B,
    const float* __restrict__ bias, const float* __restrict__ wscale,
    float* __restrict__ C, int M, int N, int K) {
    __shared__ __align__(16) unsigned char lds[131072];   // [buf:2][A 32K | B 32K]

    int nwg = gridDim.x;
    int bid = blockIdx.x;
    bid = (bid & 7) * (nwg >> 3) + (bid >> 3);   // XCD swizzle (nwg % 8 == 0)
    int ntn = N / BN;
    int tm = bid / ntn, tn = bid % ntn;
    int row0 = tm * BM, col0 = tn * BN;

    int tid = (int)threadIdx.x;
    int lane = tid & 63, wid = tid >> 6;
    int wr = wid >> 2, wc = wid & 3;             // 2M x 4N waves; per-wave 128x64
    int fr = lane & 15, g = lane >> 4;

    // ---- staging: lane's global byte offset (i-invariant swizzle) + linear LDS dest
    int srow = tid >> 3;                          // 0..63
    int sc   = (tid & 7) ^ (srow & 7);            // logical chunk col (i*64 == 0 mod 8)
    const int offA0 = (row0 + srow) * K + sc * 16;    // + i*131072 + kt
    const int offB0 = (col0 + srow) * K + sc * 16;
    unsigned char* dstA = lds + tid * 16;             // + i*8192 + buf*65536
    unsigned char* dstB = dstA + 32768;

    // ---- fragment bases: r&7 == fr&7 for all fragment rows -> one swizzle per lane
    int c0 = (2 * g) ^ (fr & 7);
    const int aL = wr * 16384 + fr * 128 + c0 * 16;        // + m*2048
    const int aH = wr * 16384 + fr * 128 + (c0 ^ 1) * 16;
    const int bL = 32768 + wc * 8192 + fr * 128 + c0 * 16; // + n*2048
    const int bH = 32768 + wc * 8192 + fr * 128 + (c0 ^ 1) * 16;

    floatx4 acc[8][4];
    #pragma unroll
    for (int m = 0; m < 8; ++m)
        #pragma unroll
        for (int n = 0; n < 4; ++n) acc[m][n] = (floatx4)(0.f);

    // prologue: stage slab 0 into buf0 (8 loads)
    GLOAD(A + offA0,          dstA);
    GLOAD(A + offA0 + 131072, dstA + 8192);
    GLOAD(A + offA0 + 262144, dstA + 16384);
    GLOAD(A + offA0 + 393216, dstA + 24576);
    GLOAD(B + offB0,          dstB);
    GLOAD(B + offB0 + 131072, dstB + 8192);
    GLOAD(B + offB0 + 262144, dstB + 16384);
    GLOAD(B + offB0 + 393216, dstB + 24576);

    #pragma unroll 2
    for (int t = 0; t < NT; ++t) {
        const int bufo = (t & 1) << 16;
        const int nbufo = bufo ^ 65536;
        const unsigned char* AbL = lds + bufo + aL;
        const unsigned char* AbH = lds + bufo + aH;
        const unsigned char* BbL = lds + bufo + bL;
        const unsigned char* BbH = lds + bufo + bH;
        unsigned char* dA = dstA + nbufo;
        unsigned char* dB = dstB + nbufo;
        const int kn = ((t + 1) & (NT - 1)) * BKQ;   // wrap keeps schedule uniform

        // ---- issue slab t+1's 8 staging loads FIRST (counted vmcnt keeps them in flight)
        GLOAD(A + kn + offA0,          dA);
        GLOAD(A + kn + offA0 + 131072, dA + 8192);
        GLOAD(A + kn + offA0 + 262144, dA + 16384);
        GLOAD(A + kn + offA0 + 393216, dA + 24576);
        GLOAD(B + kn + offB0,          dB);
        GLOAD(B + kn + offB0 + 131072, dB + 8192);
        GLOAD(B + kn + offB0 + 262144, dB + 16384);
        GLOAD(B + kn + offB0 + 393216, dB + 24576);
        SB0();
        WAIT_VM(8);          // slab t's 8 retired; t+1's 8 stay in flight
        SB0();
        BARRIER();           // all waves' slab-t staging visible

        intx8 b0, b1, b2, b3, aP0, aP1, aQ0, aQ1;
        // group 1 (12 reads): all B + A rows 0-1
        LDFRAG(b0, BbL, BbH, 0)
        LDFRAG(b1, BbL, BbH, 2048)
        LDFRAG(b2, BbL, BbH, 4096)
        LDFRAG(b3, BbL, BbH, 6144)
        LDFRAG(aP0, AbL, AbH, 0)
        LDFRAG(aP1, AbL, AbH, 2048)
        // group 2 (4 reads): A rows 2-3
        LDFRAG(aQ0, AbL, AbH, 4096)
        LDFRAG(aQ1, AbL, AbH, 6144)
        SB0(); WAIT_LGKM(4); SB0();       // group 1 complete (in-order DS returns)
        __builtin_amdgcn_s_setprio(1);
        MFMA_ROW(0, aP0)
        MFMA_ROW(1, aP1)
        __builtin_amdgcn_s_setprio(0);
        // group 3: A rows 4-5 (reuse aP regs; WAR after consumption)
        LDFRAG(aP0, AbL, AbH, 8192)
        LDFRAG(aP1, AbL, AbH, 10240)
        SB0(); WAIT_LGKM(4); SB0();       // group 2 complete
        __builtin_amdgcn_s_setprio(1);
        MFMA_ROW(2, aQ0)
        MFMA_ROW(3, aQ1)
        __builtin_amdgcn_s_setprio(0);
        // group 4: A rows 6-7
        LDFRAG(aQ0, AbL, AbH, 12288)
        LDFRAG(aQ1, AbL, AbH, 14336)
        SB0(); WAIT_LGKM(4); SB0();       // group 3 complete
        __builtin_amdgcn_s_setprio(1);
        MFMA_ROW(4, aP0)
        MFMA_ROW(5, aP1)
        __builtin_amdgcn_s_setprio(0);
        SB0(); WAIT_LGKM(0); SB0();       // group 4 complete
        __builtin_amdgcn_s_setprio(1);
        MFMA_ROW(6, aQ0)
        MFMA_ROW(7, aQ1)
        __builtin_amdgcn_s_setprio(0);
        BARRIER();           // all waves done reading buf t before t+2 gloads overwrite it
    }

    WAIT_VM(0);   // drain wrap-around staging before exit

    // epilogue: C/D layout (shape-determined): col=lane&15, row=(lane>>4)*4+j
    float wsv = *wscale;
    int crow = (lane >> 4) * 4;
    int ccol = lane & 15;
    float bv[4];
    #pragma unroll
    for (int n = 0; n < 4; ++n) bv[n] = bias[col0 + wc * 64 + n * 16 + ccol];
    #pragma unroll
    for (int m = 0; m < 8; ++m) {
        int r = row0 + wr * 128 + m * 16 + crow;
        #pragma unroll
        for (int n = 0; n < 4; ++n) {
            int c = col0 + wc * 64 + n * 16 + ccol;
            #pragma unroll
            for (int j = 0; j < 4; ++j)
                C[(long)(r + j) * N + c] = acc[m][n][j] * wsv + bv[n];
        }
    }
}

extern "C" void kernel_launch(void* const* d_in, const int* in_sizes, int n_in,
                              void* d_out, int out_size, void* d_ws, size_t ws_size,
                              hipStream_t stream) {
    const float* x      = (const float*)d_in[0];
    const float* w      = (const float*)d_in[1];
    const float* wscale = (const float*)d_in[2];
    const float* bias   = (const float*)d_in[3];
    float* out = (float*)d_out;

    const int K = 2048, N = 2048;
    const int M = in_sizes[0] / K;     // 16384

    unsigned char* ws = (unsigned char*)d_ws;
    unsigned* amax = (unsigned*)ws;                          // 4 B
    int* wq = (int*)(ws + 1024);                             // N*K   = 4.2 MB fp8
    int* xq = (int*)(ws + 1024 + (size_t)N * K);             // M*K   = 33.5 MB fp8

    hipMemsetAsync(amax, 0, 4, stream);
    k_absmax<<<2048, 256, 0, stream>>>(x, amax, (M * K) / 4);
    k_quant_w<<<1024, 256, 0, stream>>>(w, wq, (N * K) / 16);
    k_quant_x<<<2048, 256, 0, stream>>>(x, xq, amax, (M * K) / 16);

    int grid = (M / BM) * (N / BN);    // 64 * 8 = 512
    k_gemm_mx<<<grid, 512, 0, stream>>>((const unsigned char*)xq, (const unsigned char*)wq,
                                        bias, wscale, out, M, N, K);
}

// Round 6
// 149.270 us; speedup vs baseline: 1.5364x; 1.0989x over previous
//
#include <hip/hip_runtime.h>
#include <hip/hip_bf16.h>

typedef __attribute__((ext_vector_type(4))) float floatx4;
typedef __attribute__((ext_vector_type(8))) int   intx8;

#define FP8_MAX_F 448.0f
#define SCALE_EPS 1e-7f

// ------ fused pre-pass: blocks 0-1791 absmax(x); blocks 1792-2047 quantize W ------------
__global__ void k_pre(const float* __restrict__ x, unsigned* __restrict__ amax, int n4,
                      const float* __restrict__ w, int* __restrict__ wq, int nw16) {
    if (blockIdx.x < 1792) {
        __shared__ float wmax[4];
        int tid = blockIdx.x * 256 + threadIdx.x;
        int stride = 1792 * 256;
        const float4* x4 = (const float4*)x;
        float m = 0.f;
        for (int i = tid; i < n4; i += stride) {
            float4 v = x4[i];
            m = fmaxf(fmaxf(fabsf(v.x), fabsf(v.y)),
                      fmaxf(m, fmaxf(fabsf(v.z), fabsf(v.w))));
        }
        #pragma unroll
        for (int off = 32; off > 0; off >>= 1) m = fmaxf(m, __shfl_xor(m, off, 64));
        if ((threadIdx.x & 63) == 0) wmax[threadIdx.x >> 6] = m;
        __syncthreads();
        if (threadIdx.x == 0) {
            float t = fmaxf(fmaxf(wmax[0], wmax[1]), fmaxf(wmax[2], wmax[3]));
            atomicMax(amax, __float_as_uint(t));
        }
    } else {
        int tid = (blockIdx.x - 1792) * 256 + threadIdx.x;
        int stride = 256 * 256;
        const float4* x4 = (const float4*)w;
        int4* q4 = (int4*)wq;
        for (int i = tid; i < nw16; i += stride) {
            float4 v0 = x4[4*i], v1 = x4[4*i+1], v2 = x4[4*i+2], v3 = x4[4*i+3];
            int4 o;
            o.x = __builtin_amdgcn_cvt_pk_fp8_f32(v0.x, v0.y, 0, false);
            o.x = __builtin_amdgcn_cvt_pk_fp8_f32(v0.z, v0.w, o.x, true);
            o.y = __builtin_amdgcn_cvt_pk_fp8_f32(v1.x, v1.y, 0, false);
            o.y = __builtin_amdgcn_cvt_pk_fp8_f32(v1.z, v1.w, o.y, true);
            o.z = __builtin_amdgcn_cvt_pk_fp8_f32(v2.x, v2.y, 0, false);
            o.z = __builtin_amdgcn_cvt_pk_fp8_f32(v2.z, v2.w, o.z, true);
            o.w = __builtin_amdgcn_cvt_pk_fp8_f32(v3.x, v3.y, 0, false);
            o.w = __builtin_amdgcn_cvt_pk_fp8_f32(v3.z, v3.w, o.w, true);
            q4[i] = o;
        }
    }
}

// ---------------- x: f32 -> e4m3 bytes (HW RNE), scale = max(absmax/448, eps) -------------
__global__ void k_quant_x(const float* __restrict__ x, int* __restrict__ xq,
                          const unsigned* __restrict__ amax, int n16) {
    float scale = fmaxf(__uint_as_float(*amax) / FP8_MAX_F, SCALE_EPS);
    int tid = blockIdx.x * blockDim.x + threadIdx.x;
    int stride = gridDim.x * blockDim.x;
    const float4* x4 = (const float4*)x;
    int4* q4 = (int4*)xq;
    for (int i = tid; i < n16; i += stride) {
        float4 v0 = x4[4*i], v1 = x4[4*i+1], v2 = x4[4*i+2], v3 = x4[4*i+3];
        int4 o;
        o.x = __builtin_amdgcn_cvt_pk_fp8_f32(v0.x / scale, v0.y / scale, 0, false);
        o.x = __builtin_amdgcn_cvt_pk_fp8_f32(v0.z / scale, v0.w / scale, o.x, true);
        o.y = __builtin_amdgcn_cvt_pk_fp8_f32(v1.x / scale, v1.y / scale, 0, false);
        o.y = __builtin_amdgcn_cvt_pk_fp8_f32(v1.z / scale, v1.w / scale, o.y, true);
        o.z = __builtin_amdgcn_cvt_pk_fp8_f32(v2.x / scale, v2.y / scale, 0, false);
        o.z = __builtin_amdgcn_cvt_pk_fp8_f32(v2.z / scale, v2.w / scale, o.z, true);
        o.w = __builtin_amdgcn_cvt_pk_fp8_f32(v3.x / scale, v3.y / scale, 0, false);
        o.w = __builtin_amdgcn_cvt_pk_fp8_f32(v3.z / scale, v3.w / scale, o.w, true);
        q4[i] = o;
    }
}

// ================= 256x256 8-wave MX-fp8 GEMM: counted vmcnt, compiler-scheduled body =====
// C[M,N] = ws * (A[M,K]fp8 . B[N,K]fp8^T) + bias.  Slab = 128 fp8-K (one 16x16x128 step).
// Per slab: issue 8 gloads(t+1) -> vmcnt(8) (t's retired, t+1's in flight) -> barrier ->
// 12 ds_read_b128-pairs + 32 MFMA, ALL ordering left to the compiler (m97-style
// fine-grained lgkmcnt) -> barrier. No sched_barrier / setprio / manual lgkm (m141 lesson).
#define BM 256
#define BN 256
#define BKQ 128
#define NT 16   // K / BKQ, K = 2048 fixed

#define GLOAD(src, dst) \
    __builtin_amdgcn_global_load_lds((const __attribute__((address_space(1))) void*)(src), \
                                     (__attribute__((address_space(3))) void*)(dst), 16, 0, 0)
#define BARRIER()   asm volatile("s_barrier" ::: "memory")
#define WAIT_VM(n)  asm volatile("s_waitcnt vmcnt(" #n ")" ::: "memory")

#define LDFRAG(dstv, pL, pH, IMM) {                      \
    int4 lo_ = *(const int4*)((pL) + (IMM));             \
    int4 hi_ = *(const int4*)((pH) + (IMM));             \
    dstv = (intx8){lo_.x, lo_.y, lo_.z, lo_.w, hi_.x, hi_.y, hi_.z, hi_.w}; }

#define MFMA_ROW(m, af)                                                            \
    acc[m][0] = __builtin_amdgcn_mfma_scale_f32_16x16x128_f8f6f4(                  \
        af, b0, acc[m][0], 0, 0, 0, 0x7F7F7F7F, 0, 0x7F7F7F7F);                    \
    acc[m][1] = __builtin_amdgcn_mfma_scale_f32_16x16x128_f8f6f4(                  \
        af, b1, acc[m][1], 0, 0, 0, 0x7F7F7F7F, 0, 0x7F7F7F7F);                    \
    acc[m][2] = __builtin_amdgcn_mfma_scale_f32_16x16x128_f8f6f4(                  \
        af, b2, acc[m][2], 0, 0, 0, 0x7F7F7F7F, 0, 0x7F7F7F7F);                    \
    acc[m][3] = __builtin_amdgcn_mfma_scale_f32_16x16x128_f8f6f4(                  \
        af, b3, acc[m][3], 0, 0, 0, 0x7F7F7F7F, 0, 0x7F7F7F7F);

__global__ __launch_bounds__(512, 2) void k_gemm_mx(
    const unsigned char* __restrict__ A, const unsigned char* __restrict__ B,
    const float* __restrict__ bias, const float* __restrict__ wscale,
    float* __restrict__ C, int M, int N, int K) {
    __shared__ __align__(16) unsigned char lds[131072];   // [buf:2][A 32K | B 32K]

    int nwg = gridDim.x;
    int bid = blockIdx.x;
    bid = (bid & 7) * (nwg >> 3) + (bid >> 3);   // XCD swizzle (nwg % 8 == 0)
    int ntn = N / BN;
    int tm = bid / ntn, tn = bid % ntn;
    int row0 = tm * BM, col0 = tn * BN;

    int tid = (int)threadIdx.x;
    int lane = tid & 63, wid = tid >> 6;
    int wr = wid >> 2, wc = wid & 3;             // 2M x 4N waves; per-wave 128x64
    int fr = lane & 15, g = lane >> 4;

    // ---- staging: lane's global byte offset (i-invariant swizzle) + linear LDS dest
    int srow = tid >> 3;                          // 0..63
    int sc   = (tid & 7) ^ (srow & 7);            // logical chunk col (i*64 == 0 mod 8)
    const int offA0 = (row0 + srow) * K + sc * 16;    // + i*131072 + kt
    const int offB0 = (col0 + srow) * K + sc * 16;
    unsigned char* dstA = lds + tid * 16;             // + i*8192 + buf*65536
    unsigned char* dstB = dstA + 32768;

    // ---- fragment bases: r&7 == fr&7 for all fragment rows -> one swizzle per lane
    int c0 = (2 * g) ^ (fr & 7);
    const int aL = wr * 16384 + fr * 128 + c0 * 16;        // + m*2048
    const int aH = wr * 16384 + fr * 128 + (c0 ^ 1) * 16;
    const int bL = 32768 + wc * 8192 + fr * 128 + c0 * 16; // + n*2048
    const int bH = 32768 + wc * 8192 + fr * 128 + (c0 ^ 1) * 16;

    floatx4 acc[8][4];
    #pragma unroll
    for (int m = 0; m < 8; ++m)
        #pragma unroll
        for (int n = 0; n < 4; ++n) acc[m][n] = (floatx4)(0.f);

    // prologue: stage slab 0 into buf0 (8 loads)
    GLOAD(A + offA0,          dstA);
    GLOAD(A + offA0 + 131072, dstA + 8192);
    GLOAD(A + offA0 + 262144, dstA + 16384);
    GLOAD(A + offA0 + 393216, dstA + 24576);
    GLOAD(B + offB0,          dstB);
    GLOAD(B + offB0 + 131072, dstB + 8192);
    GLOAD(B + offB0 + 262144, dstB + 16384);
    GLOAD(B + offB0 + 393216, dstB + 24576);

    for (int t = 0; t < NT; ++t) {
        const int bufo = (t & 1) << 16;
        const int nbufo = bufo ^ 65536;
        const unsigned char* AbL = lds + bufo + aL;
        const unsigned char* AbH = lds + bufo + aH;
        const unsigned char* BbL = lds + bufo + bL;
        const unsigned char* BbH = lds + bufo + bH;
        unsigned char* dA = dstA + nbufo;
        unsigned char* dB = dstB + nbufo;
        const int kn = ((t + 1) & (NT - 1)) * BKQ;   // wrap keeps schedule uniform

        // issue slab t+1's 8 staging loads (counted vmcnt keeps them in flight)
        GLOAD(A + kn + offA0,          dA);
        GLOAD(A + kn + offA0 + 131072, dA + 8192);
        GLOAD(A + kn + offA0 + 262144, dA + 16384);
        GLOAD(A + kn + offA0 + 393216, dA + 24576);
        GLOAD(B + kn + offB0,          dB);
        GLOAD(B + kn + offB0 + 131072, dB + 8192);
        GLOAD(B + kn + offB0 + 262144, dB + 16384);
        GLOAD(B + kn + offB0 + 393216, dB + 24576);
        WAIT_VM(8);          // slab t's 8 retired; t+1's 8 stay in flight
        BARRIER();           // all waves' slab-t staging visible

        // body: 12 fragment loads + 32 MFMA; compiler interleaves with counted lgkmcnt
        intx8 b0, b1, b2, b3, a0, a1, a2, a3, a4, a5, a6, a7;
        LDFRAG(b0, BbL, BbH, 0)
        LDFRAG(b1, BbL, BbH, 2048)
        LDFRAG(b2, BbL, BbH, 4096)
        LDFRAG(b3, BbL, BbH, 6144)
        LDFRAG(a0, AbL, AbH, 0)
        LDFRAG(a1, AbL, AbH, 2048)
        LDFRAG(a2, AbL, AbH, 4096)
        LDFRAG(a3, AbL, AbH, 6144)
        LDFRAG(a4, AbL, AbH, 8192)
        LDFRAG(a5, AbL, AbH, 10240)
        LDFRAG(a6, AbL, AbH, 12288)
        LDFRAG(a7, AbL, AbH, 14336)
        MFMA_ROW(0, a0)
        MFMA_ROW(1, a1)
        MFMA_ROW(2, a2)
        MFMA_ROW(3, a3)
        MFMA_ROW(4, a4)
        MFMA_ROW(5, a5)
        MFMA_ROW(6, a6)
        MFMA_ROW(7, a7)
        BARRIER();           // all waves done reading buf t before t+2 gloads overwrite it
    }

    WAIT_VM(0);   // drain wrap-around staging before exit

    // epilogue: C/D layout (shape-determined): col=lane&15, row=(lane>>4)*4+j
    float wsv = *wscale;
    int crow = (lane >> 4) * 4;
    int ccol = lane & 15;
    float bv[4];
    #pragma unroll
    for (int n = 0; n < 4; ++n) bv[n] = bias[col0 + wc * 64 + n * 16 + ccol];
    #pragma unroll
    for (int m = 0; m < 8; ++m) {
        int r = row0 + wr * 128 + m * 16 + crow;
        #pragma unroll
        for (int n = 0; n < 4; ++n) {
            int c = col0 + wc * 64 + n * 16 + ccol;
            #pragma unroll
            for (int j = 0; j < 4; ++j)
                C[(long)(r + j) * N + c] = acc[m][n][j] * wsv + bv[n];
        }
    }
}

extern "C" void kernel_launch(void* const* d_in, const int* in_sizes, int n_in,
                              void* d_out, int out_size, void* d_ws, size_t ws_size,
                              hipStream_t stream) {
    const float* x      = (const float*)d_in[0];
    const float* w      = (const float*)d_in[1];
    const float* wscale = (const float*)d_in[2];
    const float* bias   = (const float*)d_in[3];
    float* out = (float*)d_out;

    const int K = 2048, N = 2048;
    const int M = in_sizes[0] / K;     // 16384

    unsigned char* ws = (unsigned char*)d_ws;
    unsigned* amax = (unsigned*)ws;                          // 4 B
    int* wq = (int*)(ws + 1024);                             // N*K   = 4.2 MB fp8
    int* xq = (int*)(ws + 1024 + (size_t)N * K);             // M*K   = 33.5 MB fp8

    hipMemsetAsync(amax, 0, 4, stream);
    k_pre<<<2048, 256, 0, stream>>>(x, amax, (M * K) / 4, w, wq, (N * K) / 16);
    k_quant_x<<<2048, 256, 0, stream>>>(x, xq, amax, (M * K) / 16);

    int grid = (M / BM) * (N / BN);    // 64 * 8 = 512
    k_gemm_mx<<<grid, 512, 0, stream>>>((const unsigned char*)xq, (const unsigned char*)wq,
                                        bias, wscale, out, M, N, K);
}